// Round 3
// baseline (1475.488 us; speedup 1.0000x reference)
//
#include <hip/hip_runtime.h>
#include <cfloat>
#include <cmath>

#define NN 40000
#define DIN 3000
#define NE 640000
#define ET (NE + NN)   // edges incl. self-loops = 680000

__device__ __forceinline__ float lrelu(float x) { return x >= 0.f ? x : 0.2f * x; }
__device__ __forceinline__ float elu(float x)   { return x > 0.f ? x : expm1f(x); }

// ---------------- Kernel A: h = elu(bn(x @ e0_w + e0_b)) ----------------
// Register-blocked split-K: block=256=4 waves, 16 rows/block, wave w owns K-range
// {768,768,768,696}. Lane (kq=l%16, rg=l/16): acc[32c][4r] in regs. Per 64-k chunk:
// wave-private transposed w tile in LDS (no block barrier in main loop), 4 float4
// x loads, 32 ds_read_b128, 512 FMA. End: shfl_xor butterfly over kq + LDS atomic.
__global__ __launch_bounds__(256, 2) void k_enc0(
    const float* __restrict__ x, const float* __restrict__ w,
    const float* __restrict__ b, const float* __restrict__ g,
    const float* __restrict__ beta, const float* __restrict__ m,
    const float* __restrict__ v, float* __restrict__ h)
{
    __shared__ float wT[4][32 * 68];   // per-wave [c][k+pad68]
    __shared__ float accT[16 * 32];    // [row][c]
    const int tid = threadIdx.x;
    const int wid = tid >> 6;
    const int l   = tid & 63;
    const int kq  = l & 15;
    const int rg  = l >> 4;
    const int row0 = blockIdx.x * 16;

    accT[tid] = 0.f;
    accT[tid + 256] = 0.f;
    __syncthreads();

    const int kbase = wid * 768;
    const int ktot  = (wid == 3) ? 696 : 768;
    float* wTw = &wT[wid][0];

    float acc[32][4];
    #pragma unroll
    for (int c = 0; c < 32; c++)
        #pragma unroll
        for (int r = 0; r < 4; r++) acc[c][r] = 0.f;

    for (int k0 = 0; k0 < ktot; k0 += 64) {
        const int kcnt = min(64, ktot - k0);   // 64 or 56 (tail, whole quads)
        // stage w[kbase+k0 .. +kcnt)[0..32) transposed: wTw[c][k]
        #pragma unroll
        for (int j = 0; j < 8; j++) {
            int i = l + j * 64;          // 0..511
            int k = i >> 3, c4 = i & 7;
            if (k < kcnt) {
                float4 wv = *(const float4*)&w[(size_t)(kbase + k0 + k) * 32 + c4 * 4];
                wTw[(c4 * 4 + 0) * 68 + k] = wv.x;
                wTw[(c4 * 4 + 1) * 68 + k] = wv.y;
                wTw[(c4 * 4 + 2) * 68 + k] = wv.z;
                wTw[(c4 * 4 + 3) * 68 + k] = wv.w;
            }
        }
        // x quads: lane's 4 rows, its k-quad
        float4 x4[4];
        const bool kv = (kq * 4) < kcnt;
        #pragma unroll
        for (int r = 0; r < 4; r++) {
            x4[r] = make_float4(0.f, 0.f, 0.f, 0.f);
            if (kv)
                x4[r] = *(const float4*)&x[(size_t)(row0 + rg * 4 + r) * DIN + kbase + k0 + kq * 4];
        }
        // wave-private LDS: writes above, reads below, same wave -> lgkmcnt drain
        asm volatile("s_waitcnt lgkmcnt(0)" ::: "memory");
        #pragma unroll
        for (int c = 0; c < 32; c++) {
            float4 wv = *(const float4*)&wTw[c * 68 + kq * 4];
            #pragma unroll
            for (int r = 0; r < 4; r++) {
                acc[c][r] += x4[r].x * wv.x;
                acc[c][r] += x4[r].y * wv.y;
                acc[c][r] += x4[r].z * wv.z;
                acc[c][r] += x4[r].w * wv.w;
            }
        }
    }

    // reduce across the 16 kq-lanes (masks <16 keep rg groups intact)
    #pragma unroll
    for (int c = 0; c < 32; c++) {
        #pragma unroll
        for (int r = 0; r < 4; r++) {
            float s = acc[c][r];
            s += __shfl_xor(s, 1);
            s += __shfl_xor(s, 2);
            s += __shfl_xor(s, 4);
            s += __shfl_xor(s, 8);
            acc[c][r] = s;
        }
    }
    // lane kq contributes columns 2kq, 2kq+1 (compile-time c, predicated)
    #pragma unroll
    for (int c = 0; c < 32; c++) {
        if ((c >> 1) == kq) {
            #pragma unroll
            for (int r = 0; r < 4; r++)
                atomicAdd(&accT[(rg * 4 + r) * 32 + c], acc[c][r]);
        }
    }
    __syncthreads();

    // BN + ELU + store: 512 values, 2 per thread
    #pragma unroll
    for (int i = 0; i < 2; i++) {
        int idx = tid + i * 256;
        int r = idx >> 5, c = idx & 31;
        float sc = g[c] * rsqrtf(v[c] + 1e-3f);
        float val = (accT[idx] + b[c]) * sc + (beta[c] - m[c] * sc);
        h[(size_t)(row0 + r) * 32 + c] = elu(val);
    }
}

// ------------- Kernel B: feat_x, hw1, attention scalars, init GAT1 atomics -------------
__global__ void k_enc1_prep(
    const float* __restrict__ h,
    const float* __restrict__ e1w, const float* __restrict__ e1b,
    const float* __restrict__ e1g, const float* __restrict__ e1beta,
    const float* __restrict__ e1m, const float* __restrict__ e1v,
    const float* __restrict__ g1w, const float* __restrict__ g1as,
    const float* __restrict__ g1ad,
    float* __restrict__ out_fx, float* __restrict__ hw1,
    float* __restrict__ s1src, float* __restrict__ s1dst,
    float* __restrict__ z1, float* __restrict__ acc1)
{
    int row = blockIdx.x * 256 + threadIdx.x;
    if (row >= NN) return;
    float hr[32];
    #pragma unroll
    for (int k = 0; k < 32; k++) hr[k] = h[(size_t)row * 32 + k];
    float fx[20];
    for (int c = 0; c < 20; c++) {
        float s = e1b[c];
        for (int k = 0; k < 32; k++) s += hr[k] * e1w[k * 20 + c];
        float sc = e1g[c] * rsqrtf(e1v[c] + 1e-3f);
        s = (s - e1m[c]) * sc + e1beta[c];
        fx[c] = elu(s);
        out_fx[(size_t)row * 20 + c] = fx[c];
    }
    float ss = 0.f, sd = 0.f;
    for (int c = 0; c < 64; c++) {
        float s = 0.f;
        for (int k = 0; k < 20; k++) s += fx[k] * g1w[k * 64 + c];
        hw1[(size_t)row * 64 + c] = s;
        ss += s * g1as[c];
        sd += s * g1ad[c];
        acc1[(size_t)row * 64 + c] = 0.f;
    }
    s1src[row] = ss; s1dst[row] = sd;
    z1[row] = 0.f;
}

// ------------- Kernel D: GAT1 numerator/denominator accumulate (64 lanes/edge) -------------
// softmax is shift-invariant: use exp(al) directly (logits bounded ~|3|), skip max pass.
__global__ __launch_bounds__(256) void k_gat1_acc(const int* __restrict__ ei,
    const float* __restrict__ s1src, const float* __restrict__ s1dst,
    const float* __restrict__ hw1,
    float* __restrict__ z1, float* __restrict__ acc1)
{
    int t = blockIdx.x * 256 + threadIdx.x;
    int lane = t & 63;
    int e = t >> 6;
    if (e >= ET) return;
    int s, d;
    if (e < NE) { s = ei[e]; d = ei[NE + e]; } else { s = d = e - NE; }
    float al = lrelu(s1src[s] + s1dst[d]);
    float ex = expf(al);
    if (lane == 0) atomicAdd(&z1[d], ex);
    atomicAdd(&acc1[(size_t)d * 64 + lane], ex * hw1[(size_t)s * 64 + lane]);
}

// ------------- Kernel E: normalize GAT1, BN+ReLU -> c; hw_m/hw_v + scalars; init atomics -------------
__global__ void k_gat1_norm(
    const float* __restrict__ acc1, const float* __restrict__ z1,
    const float* __restrict__ g1b,
    const float* __restrict__ bncg, const float* __restrict__ bncbeta,
    const float* __restrict__ bncm, const float* __restrict__ bncv,
    const float* __restrict__ gmw, const float* __restrict__ gmas, const float* __restrict__ gmad,
    const float* __restrict__ gvw, const float* __restrict__ gvas, const float* __restrict__ gvad,
    float* __restrict__ hwm, float* __restrict__ hwv,
    float* __restrict__ smsrc, float* __restrict__ smdst,
    float* __restrict__ svsrc, float* __restrict__ svdst,
    float* __restrict__ zm, float* __restrict__ zv,
    float* __restrict__ accm, float* __restrict__ accv)
{
    int row = blockIdx.x * 256 + threadIdx.x;
    if (row >= NN) return;
    float zi = 1.f / (z1[row] + 1e-16f);
    float c[64];
    for (int f = 0; f < 64; f++) {
        float val = acc1[(size_t)row * 64 + f] * zi + g1b[f];
        float sc = bncg[f] * rsqrtf(bncv[f] + 1e-5f);
        val = (val - bncm[f]) * sc + bncbeta[f];
        c[f] = val > 0.f ? val : 0.f;
    }
    float ssm = 0.f, sdm = 0.f, ssv = 0.f, sdv = 0.f;
    for (int o = 0; o < 8; o++) {
        float sm = 0.f, sv = 0.f;
        for (int k = 0; k < 64; k++) {
            sm += c[k] * gmw[k * 8 + o];
            sv += c[k] * gvw[k * 8 + o];
        }
        hwm[(size_t)row * 8 + o] = sm; hwv[(size_t)row * 8 + o] = sv;
        ssm += sm * gmas[o]; sdm += sm * gmad[o];
        ssv += sv * gvas[o]; sdv += sv * gvad[o];
        accm[(size_t)row * 8 + o] = 0.f; accv[(size_t)row * 8 + o] = 0.f;
    }
    smsrc[row] = ssm; smdst[row] = sdm;
    svsrc[row] = ssv; svdst[row] = sdv;
    zm[row] = 0.f;
    zv[row] = 0.f;
}

// ------------- Kernel G: mu/logvar GAT accumulate (8 lanes/edge), no max pass -------------
__global__ __launch_bounds__(256) void k_gat23_acc(const int* __restrict__ ei,
    const float* __restrict__ smsrc, const float* __restrict__ smdst,
    const float* __restrict__ svsrc, const float* __restrict__ svdst,
    const float* __restrict__ hwm, const float* __restrict__ hwv,
    float* __restrict__ zm, float* __restrict__ accm,
    float* __restrict__ zv, float* __restrict__ accv)
{
    int t = blockIdx.x * 256 + threadIdx.x;
    int lane = t & 7;
    int e = t >> 3;
    if (e >= ET) return;
    int s, d;
    if (e < NE) { s = ei[e]; d = ei[NE + e]; } else { s = d = e - NE; }
    float am = lrelu(smsrc[s] + smdst[d]);
    float exm = expf(am);
    if (lane == 0) atomicAdd(&zm[d], exm);
    atomicAdd(&accm[(size_t)d * 8 + lane], exm * hwm[(size_t)s * 8 + lane]);
    float av = lrelu(svsrc[s] + svdst[d]);
    float exv = expf(av);
    if (lane == 0) atomicAdd(&zv[d], exv);
    atomicAdd(&accv[(size_t)d * 8 + lane], exv * hwv[(size_t)s * 8 + lane]);
}

// ------------- Kernel H: mu/logvar/gnn_z/z, decoder L0, student-t q -------------
__global__ void k_final(
    const float* __restrict__ accm, const float* __restrict__ zm, const float* __restrict__ gmb,
    const float* __restrict__ accv, const float* __restrict__ zv, const float* __restrict__ gvb,
    const float* __restrict__ epsin, const float* __restrict__ fx_out,
    const float* __restrict__ d0w, const float* __restrict__ d0b,
    const float* __restrict__ d0g, const float* __restrict__ d0beta,
    const float* __restrict__ d0m, const float* __restrict__ d0v,
    const float* __restrict__ cluster,
    float* __restrict__ out_z, float* __restrict__ out_mu, float* __restrict__ out_lv,
    float* __restrict__ out_q, float* __restrict__ out_gz, float* __restrict__ dbuf)
{
    int row = blockIdx.x * 256 + threadIdx.x;
    if (row >= NN) return;
    float zvec[28];
    #pragma unroll
    for (int k = 0; k < 20; k++) zvec[k] = fx_out[(size_t)row * 20 + k];
    float zim = 1.f / (zm[row] + 1e-16f);
    float ziv = 1.f / (zv[row] + 1e-16f);
    #pragma unroll
    for (int o = 0; o < 8; o++) {
        float mu = accm[(size_t)row * 8 + o] * zim + gmb[o];
        float lv = accv[(size_t)row * 8 + o] * ziv + gvb[o];
        float gz = epsin[(size_t)row * 8 + o] * expf(lv) + mu;
        out_mu[(size_t)row * 8 + o] = mu;
        out_lv[(size_t)row * 8 + o] = lv;
        out_gz[(size_t)row * 8 + o] = gz;
        zvec[20 + o] = gz;
    }
    #pragma unroll
    for (int k = 0; k < 28; k++) out_z[(size_t)row * 28 + k] = zvec[k];
    // decoder L0: elu(bn(z @ d0_w + d0_b))
    for (int c = 0; c < 32; c++) {
        float s = d0b[c];
        for (int k = 0; k < 28; k++) s += zvec[k] * d0w[k * 32 + c];
        float sc = d0g[c] * rsqrtf(d0v[c] + 1e-3f);
        s = (s - d0m[c]) * sc + d0beta[c];
        dbuf[(size_t)row * 32 + c] = elu(s);
    }
    // student-t q
    float zz = 0.f;
    #pragma unroll
    for (int k = 0; k < 28; k++) zz += zvec[k] * zvec[k];
    float qv[15], qs = 0.f;
    for (int j = 0; j < 15; j++) {
        float cc = 0.f, zc = 0.f;
        for (int k = 0; k < 28; k++) {
            float cv = cluster[j * 28 + k];
            cc += cv * cv; zc += zvec[k] * cv;
        }
        float sq = zz + cc - 2.f * zc;
        if (sq < 0.f) sq = 0.f;
        float qb = 1.f / (1.f + sq * (1.f / 0.9f) + 1e-8f);
        qb = powf(qb, 0.95f);
        qv[j] = qb; qs += qb;
    }
    float qi = 1.f / qs;
    #pragma unroll
    for (int j = 0; j < 15; j++) out_q[(size_t)row * 15 + j] = qv[j] * qi;
}

// ------------- Kernel I: de_feat = d @ out_w + out_b -------------
// Tiled: 64 rows x 256 cols per block. LDS: w tile [32][256] (32KB) + d tile
// [64][32] (8KB). Thread = 16 rows x 4 cols (float4). float4 loads/stores.
#define DQ 750   // DIN/4 quads per row
__global__ __launch_bounds__(256) void k_dec_out(
    const float* __restrict__ dbuf, const float* __restrict__ ow,
    const float* __restrict__ ob, float* __restrict__ out_de)
{
    __shared__ float4 wt[32 * 64];   // [k][quad]
    __shared__ float  dt[64 * 32];   // [row][k]
    const int tid = threadIdx.x;
    const int cq0 = blockIdx.x * 64;      // quad base in output row
    const int row0 = blockIdx.y * 64;

    // load w tile: 32 k-rows x 64 quads
    #pragma unroll
    for (int i = 0; i < 8; i++) {
        int t = tid + i * 256;            // 0..2047
        int k = t >> 6, lq = t & 63;
        int gq = cq0 + lq;
        wt[t] = (gq < DQ) ? ((const float4*)ow)[(size_t)k * DQ + gq]
                          : make_float4(0.f, 0.f, 0.f, 0.f);
    }
    // load d tile: 64 rows x 32 = 512 float4
    #pragma unroll
    for (int i = 0; i < 2; i++) {
        int t = tid + i * 256;
        ((float4*)dt)[t] = ((const float4*)dbuf)[(size_t)row0 * 8 + t];
    }
    __syncthreads();

    const int qid = tid & 63;
    const int rg  = tid >> 6;             // wave-uniform row group (0..3)
    const int q   = cq0 + qid;
    const bool valid = q < DQ;

    float4 acc[16];
    #pragma unroll
    for (int r = 0; r < 16; r++) acc[r] = make_float4(0.f, 0.f, 0.f, 0.f);

    #pragma unroll
    for (int k4 = 0; k4 < 8; k4++) {
        float4 w0 = wt[(k4 * 4 + 0) * 64 + qid];
        float4 w1 = wt[(k4 * 4 + 1) * 64 + qid];
        float4 w2 = wt[(k4 * 4 + 2) * 64 + qid];
        float4 w3 = wt[(k4 * 4 + 3) * 64 + qid];
        #pragma unroll
        for (int r = 0; r < 16; r++) {
            float4 dq = *(const float4*)&dt[(rg * 16 + r) * 32 + k4 * 4]; // broadcast
            acc[r].x += dq.x * w0.x; acc[r].y += dq.x * w0.y;
            acc[r].z += dq.x * w0.z; acc[r].w += dq.x * w0.w;
            acc[r].x += dq.y * w1.x; acc[r].y += dq.y * w1.y;
            acc[r].z += dq.y * w1.z; acc[r].w += dq.y * w1.w;
            acc[r].x += dq.z * w2.x; acc[r].y += dq.z * w2.y;
            acc[r].z += dq.z * w2.z; acc[r].w += dq.z * w2.w;
            acc[r].x += dq.w * w3.x; acc[r].y += dq.w * w3.y;
            acc[r].z += dq.w * w3.z; acc[r].w += dq.w * w3.w;
        }
    }

    if (valid) {
        float4 bq = ((const float4*)ob)[q];
        #pragma unroll
        for (int r = 0; r < 16; r++) {
            float4 o;
            o.x = acc[r].x + bq.x; o.y = acc[r].y + bq.y;
            o.z = acc[r].z + bq.z; o.w = acc[r].w + bq.w;
            ((float4*)out_de)[(size_t)(row0 + rg * 16 + r) * DQ + q] = o;
        }
    }
}

extern "C" void kernel_launch(void* const* d_in, const int* in_sizes, int n_in,
                              void* d_out, int out_size, void* d_ws, size_t ws_size,
                              hipStream_t stream) {
    const float* x      = (const float*)d_in[0];
    const int*   ei     = (const int*)  d_in[1];
    const float* e0_w   = (const float*)d_in[2];
    const float* e0_b   = (const float*)d_in[3];
    const float* e0_g   = (const float*)d_in[4];
    const float* e0_be  = (const float*)d_in[5];
    const float* e0_m   = (const float*)d_in[6];
    const float* e0_v   = (const float*)d_in[7];
    const float* e1_w   = (const float*)d_in[8];
    const float* e1_b   = (const float*)d_in[9];
    const float* e1_g   = (const float*)d_in[10];
    const float* e1_be  = (const float*)d_in[11];
    const float* e1_m   = (const float*)d_in[12];
    const float* e1_v   = (const float*)d_in[13];
    const float* g1_w   = (const float*)d_in[14];
    const float* g1_as  = (const float*)d_in[15];
    const float* g1_ad  = (const float*)d_in[16];
    const float* g1_b   = (const float*)d_in[17];
    const float* bnc_g  = (const float*)d_in[18];
    const float* bnc_be = (const float*)d_in[19];
    const float* bnc_m  = (const float*)d_in[20];
    const float* bnc_v  = (const float*)d_in[21];
    const float* gm_w   = (const float*)d_in[22];
    const float* gm_as  = (const float*)d_in[23];
    const float* gm_ad  = (const float*)d_in[24];
    const float* gm_b   = (const float*)d_in[25];
    const float* gv_w   = (const float*)d_in[26];
    const float* gv_as  = (const float*)d_in[27];
    const float* gv_ad  = (const float*)d_in[28];
    const float* gv_b   = (const float*)d_in[29];
    const float* d0_w   = (const float*)d_in[30];
    const float* d0_b   = (const float*)d_in[31];
    const float* d0_g   = (const float*)d_in[32];
    const float* d0_be  = (const float*)d_in[33];
    const float* d0_m   = (const float*)d_in[34];
    const float* d0_v   = (const float*)d_in[35];
    const float* out_w  = (const float*)d_in[36];
    const float* out_b  = (const float*)d_in[37];
    const float* cluster= (const float*)d_in[38];
    const float* epsin  = (const float*)d_in[39];

    float* out = (float*)d_out;
    // output offsets (floats), return order: z, mu, logvar, de_feat, q, feat_x, gnn_z
    float* out_z  = out;
    float* out_mu = out + (size_t)NN * 28;
    float* out_lv = out + (size_t)NN * 36;
    float* out_de = out + (size_t)NN * 44;
    float* out_q  = out + (size_t)NN * 44 + (size_t)NN * DIN;
    float* out_fx = out + (size_t)NN * 59 + (size_t)NN * DIN;
    float* out_gz = out + (size_t)NN * 79 + (size_t)NN * DIN;

    float* ws = (float*)d_ws;
    const size_t n = NN;
    // phase-1 layout
    float* hw1   = ws;                 // 64N
    float* acc1  = ws + 64 * n;        // 64N
    float* hbuf  = ws + 128 * n;       // 32N (h, later reused as dbuf)
    float* s1src = ws + 160 * n;
    float* s1dst = ws + 161 * n;
    float* z1    = ws + 162 * n;
    // phase-2 layout (reuses hw1's 64N block after GAT1 is done)
    float* hwm   = ws;                 // 8N
    float* hwv   = ws + 8 * n;         // 8N
    float* smsrc = ws + 16 * n;
    float* smdst = ws + 17 * n;
    float* svsrc = ws + 18 * n;
    float* svdst = ws + 19 * n;
    float* zm    = ws + 20 * n;
    float* zv    = ws + 21 * n;
    float* accm  = ws + 24 * n;        // 8N
    float* accv  = ws + 32 * n;        // 8N
    float* dbuf  = hbuf;               // 32N

    const int NB_ROWS = (NN + 255) / 256;  // 157

    k_enc0<<<NN / 16, 256, 0, stream>>>(x, e0_w, e0_b, e0_g, e0_be, e0_m, e0_v, hbuf);
    k_enc1_prep<<<NB_ROWS, 256, 0, stream>>>(hbuf, e1_w, e1_b, e1_g, e1_be, e1_m, e1_v,
                                             g1_w, g1_as, g1_ad,
                                             out_fx, hw1, s1src, s1dst, z1, acc1);
    k_gat1_acc<<<(ET * 64) / 256, 256, 0, stream>>>(ei, s1src, s1dst, hw1, z1, acc1);
    k_gat1_norm<<<NB_ROWS, 256, 0, stream>>>(acc1, z1, g1_b, bnc_g, bnc_be, bnc_m, bnc_v,
                                             gm_w, gm_as, gm_ad, gv_w, gv_as, gv_ad,
                                             hwm, hwv, smsrc, smdst, svsrc, svdst,
                                             zm, zv, accm, accv);
    k_gat23_acc<<<(ET * 8) / 256, 256, 0, stream>>>(ei, smsrc, smdst, svsrc, svdst,
                                                    hwm, hwv, zm, accm, zv, accv);
    k_final<<<NB_ROWS, 256, 0, stream>>>(accm, zm, gm_b, accv, zv, gv_b, epsin, out_fx,
                                         d0_w, d0_b, d0_g, d0_be, d0_m, d0_v, cluster,
                                         out_z, out_mu, out_lv, out_q, out_gz, dbuf);
    dim3 dec_grid((DQ + 63) / 64, NN / 64);
    k_dec_out<<<dec_grid, 256, 0, stream>>>(dbuf, out_w, out_b, out_de);
}

// Round 4
// 946.203 us; speedup vs baseline: 1.5594x; 1.5594x over previous
//
#include <hip/hip_runtime.h>
#include <cfloat>
#include <cmath>

#define NN 40000
#define DIN 3000
#define NE 640000
#define ET (NE + NN)   // edges incl. self-loops = 680000

__device__ __forceinline__ float lrelu(float x) { return x >= 0.f ? x : 0.2f * x; }
__device__ __forceinline__ float elu(float x)   { return x > 0.f ? x : expm1f(x); }

// ---------------- Kernel A: h = elu(bn(x @ e0_w + e0_b)) ----------------
// Block = 256 threads = 256 rows x 32 cols. Thread = 4 rows x 8 cols (acc[4][2]
// float4 = 32 VGPR). w staged in LDS per 200-k chunk; x loaded as coalesced
// float4 with 1-step prefetch. Inner 4-k step: 4 glb + 8 lds + 128 FMA.
__global__ __launch_bounds__(256, 4) void k_enc0(
    const float* __restrict__ x, const float* __restrict__ w,
    const float* __restrict__ b, const float* __restrict__ g,
    const float* __restrict__ beta, const float* __restrict__ m,
    const float* __restrict__ v, float* __restrict__ h)
{
    __shared__ float wt[200 * 32];
    const int tid = threadIdx.x;
    const int c0 = (tid & 3) * 8;      // col base: 0,8,16,24
    const int rg = tid >> 2;           // row group 0..63
    const int row0 = blockIdx.x * 256 + rg * 4;

    size_t xo[4];
    #pragma unroll
    for (int r = 0; r < 4; r++) {
        int rr = row0 + r; if (rr > NN - 1) rr = NN - 1;   // clamp tail
        xo[r] = (size_t)rr * DIN;
    }

    float4 acc[4][2];
    #pragma unroll
    for (int r = 0; r < 4; r++) {
        acc[r][0] = make_float4(0.f, 0.f, 0.f, 0.f);
        acc[r][1] = make_float4(0.f, 0.f, 0.f, 0.f);
    }

    for (int kc = 0; kc < DIN; kc += 200) {
        __syncthreads();
        // stage w[kc..kc+200)[0..32): 6400 contiguous floats = 1600 float4
        for (int i = tid; i < 1600; i += 256)
            ((float4*)wt)[i] = ((const float4*)(w + (size_t)kc * 32))[i];
        __syncthreads();

        float4 xv[4];
        #pragma unroll
        for (int r = 0; r < 4; r++)
            xv[r] = *(const float4*)&x[xo[r] + kc];

        for (int s = 0; s < 50; s++) {
            float4 xn[4];
            if (s < 49) {
                #pragma unroll
                for (int r = 0; r < 4; r++)
                    xn[r] = *(const float4*)&x[xo[r] + kc + (s + 1) * 4];
            }
            const float* wr = &wt[s * 128];
            #pragma unroll
            for (int i = 0; i < 4; i++) {
                float4 w0 = *(const float4*)&wr[i * 32 + c0];
                float4 w1 = *(const float4*)&wr[i * 32 + c0 + 4];
                #pragma unroll
                for (int r = 0; r < 4; r++) {
                    float xs = (i == 0) ? xv[r].x : (i == 1) ? xv[r].y
                             : (i == 2) ? xv[r].z : xv[r].w;
                    acc[r][0].x += xs * w0.x; acc[r][0].y += xs * w0.y;
                    acc[r][0].z += xs * w0.z; acc[r][0].w += xs * w0.w;
                    acc[r][1].x += xs * w1.x; acc[r][1].y += xs * w1.y;
                    acc[r][1].z += xs * w1.z; acc[r][1].w += xs * w1.w;
                }
            }
            if (s < 49) {
                #pragma unroll
                for (int r = 0; r < 4; r++) xv[r] = xn[r];
            }
        }
    }

    // fused BN + ELU epilogue
    float sc[8], sh[8], bb[8];
    #pragma unroll
    for (int j = 0; j < 8; j++) {
        int c = c0 + j;
        sc[j] = g[c] * rsqrtf(v[c] + 1e-3f);
        sh[j] = beta[c] - m[c] * sc[j];
        bb[j] = b[c];
    }
    #pragma unroll
    for (int r = 0; r < 4; r++) {
        int row = row0 + r;
        if (row < NN) {
            float4 o0, o1;
            o0.x = elu((acc[r][0].x + bb[0]) * sc[0] + sh[0]);
            o0.y = elu((acc[r][0].y + bb[1]) * sc[1] + sh[1]);
            o0.z = elu((acc[r][0].z + bb[2]) * sc[2] + sh[2]);
            o0.w = elu((acc[r][0].w + bb[3]) * sc[3] + sh[3]);
            o1.x = elu((acc[r][1].x + bb[4]) * sc[4] + sh[4]);
            o1.y = elu((acc[r][1].y + bb[5]) * sc[5] + sh[5]);
            o1.z = elu((acc[r][1].z + bb[6]) * sc[6] + sh[6]);
            o1.w = elu((acc[r][1].w + bb[7]) * sc[7] + sh[7]);
            *(float4*)&h[(size_t)row * 32 + c0]     = o0;
            *(float4*)&h[(size_t)row * 32 + c0 + 4] = o1;
        }
    }
}

// ------------- Kernel B: feat_x, hw1, attention scalars, init GAT1 atomics -------------
__global__ void k_enc1_prep(
    const float* __restrict__ h,
    const float* __restrict__ e1w, const float* __restrict__ e1b,
    const float* __restrict__ e1g, const float* __restrict__ e1beta,
    const float* __restrict__ e1m, const float* __restrict__ e1v,
    const float* __restrict__ g1w, const float* __restrict__ g1as,
    const float* __restrict__ g1ad,
    float* __restrict__ out_fx, float* __restrict__ hw1,
    float* __restrict__ s1src, float* __restrict__ s1dst,
    float* __restrict__ z1, float* __restrict__ acc1)
{
    int row = blockIdx.x * 256 + threadIdx.x;
    if (row >= NN) return;
    float hr[32];
    #pragma unroll
    for (int k = 0; k < 32; k++) hr[k] = h[(size_t)row * 32 + k];
    float fx[20];
    for (int c = 0; c < 20; c++) {
        float s = e1b[c];
        for (int k = 0; k < 32; k++) s += hr[k] * e1w[k * 20 + c];
        float sc = e1g[c] * rsqrtf(e1v[c] + 1e-3f);
        s = (s - e1m[c]) * sc + e1beta[c];
        fx[c] = elu(s);
        out_fx[(size_t)row * 20 + c] = fx[c];
    }
    float ss = 0.f, sd = 0.f;
    for (int c = 0; c < 64; c++) {
        float s = 0.f;
        for (int k = 0; k < 20; k++) s += fx[k] * g1w[k * 64 + c];
        hw1[(size_t)row * 64 + c] = s;
        ss += s * g1as[c];
        sd += s * g1ad[c];
        acc1[(size_t)row * 64 + c] = 0.f;
    }
    s1src[row] = ss; s1dst[row] = sd;
    z1[row] = 0.f;
}

// ------------- Kernel D: GAT1 numerator/denominator accumulate (64 lanes/edge) -------------
// softmax is shift-invariant: use exp(al) directly (logits bounded ~|3|), skip max pass.
__global__ __launch_bounds__(256) void k_gat1_acc(const int* __restrict__ ei,
    const float* __restrict__ s1src, const float* __restrict__ s1dst,
    const float* __restrict__ hw1,
    float* __restrict__ z1, float* __restrict__ acc1)
{
    int t = blockIdx.x * 256 + threadIdx.x;
    int lane = t & 63;
    int e = t >> 6;
    if (e >= ET) return;
    int s, d;
    if (e < NE) { s = ei[e]; d = ei[NE + e]; } else { s = d = e - NE; }
    float al = lrelu(s1src[s] + s1dst[d]);
    float ex = expf(al);
    if (lane == 0) atomicAdd(&z1[d], ex);
    atomicAdd(&acc1[(size_t)d * 64 + lane], ex * hw1[(size_t)s * 64 + lane]);
}

// ------------- Kernel E: normalize GAT1, BN+ReLU -> c; hw_m/hw_v + scalars; init atomics -------------
__global__ void k_gat1_norm(
    const float* __restrict__ acc1, const float* __restrict__ z1,
    const float* __restrict__ g1b,
    const float* __restrict__ bncg, const float* __restrict__ bncbeta,
    const float* __restrict__ bncm, const float* __restrict__ bncv,
    const float* __restrict__ gmw, const float* __restrict__ gmas, const float* __restrict__ gmad,
    const float* __restrict__ gvw, const float* __restrict__ gvas, const float* __restrict__ gvad,
    float* __restrict__ hwm, float* __restrict__ hwv,
    float* __restrict__ smsrc, float* __restrict__ smdst,
    float* __restrict__ svsrc, float* __restrict__ svdst,
    float* __restrict__ zm, float* __restrict__ zv,
    float* __restrict__ accm, float* __restrict__ accv)
{
    int row = blockIdx.x * 256 + threadIdx.x;
    if (row >= NN) return;
    float zi = 1.f / (z1[row] + 1e-16f);
    float c[64];
    for (int f = 0; f < 64; f++) {
        float val = acc1[(size_t)row * 64 + f] * zi + g1b[f];
        float sc = bncg[f] * rsqrtf(bncv[f] + 1e-5f);
        val = (val - bncm[f]) * sc + bncbeta[f];
        c[f] = val > 0.f ? val : 0.f;
    }
    float ssm = 0.f, sdm = 0.f, ssv = 0.f, sdv = 0.f;
    for (int o = 0; o < 8; o++) {
        float sm = 0.f, sv = 0.f;
        for (int k = 0; k < 64; k++) {
            sm += c[k] * gmw[k * 8 + o];
            sv += c[k] * gvw[k * 8 + o];
        }
        hwm[(size_t)row * 8 + o] = sm; hwv[(size_t)row * 8 + o] = sv;
        ssm += sm * gmas[o]; sdm += sm * gmad[o];
        ssv += sv * gvas[o]; sdv += sv * gvad[o];
        accm[(size_t)row * 8 + o] = 0.f; accv[(size_t)row * 8 + o] = 0.f;
    }
    smsrc[row] = ssm; smdst[row] = sdm;
    svsrc[row] = ssv; svdst[row] = sdv;
    zm[row] = 0.f;
    zv[row] = 0.f;
}

// ------------- Kernel G: mu/logvar GAT accumulate (8 lanes/edge), no max pass -------------
__global__ __launch_bounds__(256) void k_gat23_acc(const int* __restrict__ ei,
    const float* __restrict__ smsrc, const float* __restrict__ smdst,
    const float* __restrict__ svsrc, const float* __restrict__ svdst,
    const float* __restrict__ hwm, const float* __restrict__ hwv,
    float* __restrict__ zm, float* __restrict__ accm,
    float* __restrict__ zv, float* __restrict__ accv)
{
    int t = blockIdx.x * 256 + threadIdx.x;
    int lane = t & 7;
    int e = t >> 3;
    if (e >= ET) return;
    int s, d;
    if (e < NE) { s = ei[e]; d = ei[NE + e]; } else { s = d = e - NE; }
    float am = lrelu(smsrc[s] + smdst[d]);
    float exm = expf(am);
    if (lane == 0) atomicAdd(&zm[d], exm);
    atomicAdd(&accm[(size_t)d * 8 + lane], exm * hwm[(size_t)s * 8 + lane]);
    float av = lrelu(svsrc[s] + svdst[d]);
    float exv = expf(av);
    if (lane == 0) atomicAdd(&zv[d], exv);
    atomicAdd(&accv[(size_t)d * 8 + lane], exv * hwv[(size_t)s * 8 + lane]);
}

// ------------- Kernel H: mu/logvar/gnn_z/z, decoder L0, student-t q -------------
__global__ void k_final(
    const float* __restrict__ accm, const float* __restrict__ zm, const float* __restrict__ gmb,
    const float* __restrict__ accv, const float* __restrict__ zv, const float* __restrict__ gvb,
    const float* __restrict__ epsin, const float* __restrict__ fx_out,
    const float* __restrict__ d0w, const float* __restrict__ d0b,
    const float* __restrict__ d0g, const float* __restrict__ d0beta,
    const float* __restrict__ d0m, const float* __restrict__ d0v,
    const float* __restrict__ cluster,
    float* __restrict__ out_z, float* __restrict__ out_mu, float* __restrict__ out_lv,
    float* __restrict__ out_q, float* __restrict__ out_gz, float* __restrict__ dbuf)
{
    int row = blockIdx.x * 256 + threadIdx.x;
    if (row >= NN) return;
    float zvec[28];
    #pragma unroll
    for (int k = 0; k < 20; k++) zvec[k] = fx_out[(size_t)row * 20 + k];
    float zim = 1.f / (zm[row] + 1e-16f);
    float ziv = 1.f / (zv[row] + 1e-16f);
    #pragma unroll
    for (int o = 0; o < 8; o++) {
        float mu = accm[(size_t)row * 8 + o] * zim + gmb[o];
        float lv = accv[(size_t)row * 8 + o] * ziv + gvb[o];
        float gz = epsin[(size_t)row * 8 + o] * expf(lv) + mu;
        out_mu[(size_t)row * 8 + o] = mu;
        out_lv[(size_t)row * 8 + o] = lv;
        out_gz[(size_t)row * 8 + o] = gz;
        zvec[20 + o] = gz;
    }
    #pragma unroll
    for (int k = 0; k < 28; k++) out_z[(size_t)row * 28 + k] = zvec[k];
    // decoder L0: elu(bn(z @ d0_w + d0_b))
    for (int c = 0; c < 32; c++) {
        float s = d0b[c];
        for (int k = 0; k < 28; k++) s += zvec[k] * d0w[k * 32 + c];
        float sc = d0g[c] * rsqrtf(d0v[c] + 1e-3f);
        s = (s - d0m[c]) * sc + d0beta[c];
        dbuf[(size_t)row * 32 + c] = elu(s);
    }
    // student-t q
    float zz = 0.f;
    #pragma unroll
    for (int k = 0; k < 28; k++) zz += zvec[k] * zvec[k];
    float qv[15], qs = 0.f;
    for (int j = 0; j < 15; j++) {
        float cc = 0.f, zc = 0.f;
        for (int k = 0; k < 28; k++) {
            float cv = cluster[j * 28 + k];
            cc += cv * cv; zc += zvec[k] * cv;
        }
        float sq = zz + cc - 2.f * zc;
        if (sq < 0.f) sq = 0.f;
        float qb = 1.f / (1.f + sq * (1.f / 0.9f) + 1e-8f);
        qb = powf(qb, 0.95f);
        qv[j] = qb; qs += qb;
    }
    float qi = 1.f / qs;
    #pragma unroll
    for (int j = 0; j < 15; j++) out_q[(size_t)row * 15 + j] = qv[j] * qi;
}

// ------------- Kernel I: de_feat = d @ out_w + out_b -------------
// Tiled: 64 rows x 256 cols per block. LDS: w tile [32][256] (32KB) + d tile
// [64][32] (8KB). Thread = 16 rows x 4 cols (float4). float4 loads/stores.
#define DQ 750   // DIN/4 quads per row
__global__ __launch_bounds__(256) void k_dec_out(
    const float* __restrict__ dbuf, const float* __restrict__ ow,
    const float* __restrict__ ob, float* __restrict__ out_de)
{
    __shared__ float4 wt[32 * 64];   // [k][quad]
    __shared__ float  dt[64 * 32];   // [row][k]
    const int tid = threadIdx.x;
    const int cq0 = blockIdx.x * 64;      // quad base in output row
    const int row0 = blockIdx.y * 64;

    // load w tile: 32 k-rows x 64 quads
    #pragma unroll
    for (int i = 0; i < 8; i++) {
        int t = tid + i * 256;            // 0..2047
        int k = t >> 6, lq = t & 63;
        int gq = cq0 + lq;
        wt[t] = (gq < DQ) ? ((const float4*)ow)[(size_t)k * DQ + gq]
                          : make_float4(0.f, 0.f, 0.f, 0.f);
    }
    // load d tile: 64 rows x 32 = 512 float4
    #pragma unroll
    for (int i = 0; i < 2; i++) {
        int t = tid + i * 256;
        ((float4*)dt)[t] = ((const float4*)dbuf)[(size_t)row0 * 8 + t];
    }
    __syncthreads();

    const int qid = tid & 63;
    const int rg  = tid >> 6;             // wave-uniform row group (0..3)
    const int q   = cq0 + qid;
    const bool valid = q < DQ;

    float4 acc[16];
    #pragma unroll
    for (int r = 0; r < 16; r++) acc[r] = make_float4(0.f, 0.f, 0.f, 0.f);

    #pragma unroll
    for (int k4 = 0; k4 < 8; k4++) {
        float4 w0 = wt[(k4 * 4 + 0) * 64 + qid];
        float4 w1 = wt[(k4 * 4 + 1) * 64 + qid];
        float4 w2 = wt[(k4 * 4 + 2) * 64 + qid];
        float4 w3 = wt[(k4 * 4 + 3) * 64 + qid];
        #pragma unroll
        for (int r = 0; r < 16; r++) {
            float4 dq = *(const float4*)&dt[(rg * 16 + r) * 32 + k4 * 4]; // broadcast
            acc[r].x += dq.x * w0.x; acc[r].y += dq.x * w0.y;
            acc[r].z += dq.x * w0.z; acc[r].w += dq.x * w0.w;
            acc[r].x += dq.y * w1.x; acc[r].y += dq.y * w1.y;
            acc[r].z += dq.y * w1.z; acc[r].w += dq.y * w1.w;
            acc[r].x += dq.z * w2.x; acc[r].y += dq.z * w2.y;
            acc[r].z += dq.z * w2.z; acc[r].w += dq.z * w2.w;
            acc[r].x += dq.w * w3.x; acc[r].y += dq.w * w3.y;
            acc[r].z += dq.w * w3.z; acc[r].w += dq.w * w3.w;
        }
    }

    if (valid) {
        float4 bq = ((const float4*)ob)[q];
        #pragma unroll
        for (int r = 0; r < 16; r++) {
            float4 o;
            o.x = acc[r].x + bq.x; o.y = acc[r].y + bq.y;
            o.z = acc[r].z + bq.z; o.w = acc[r].w + bq.w;
            ((float4*)out_de)[(size_t)(row0 + rg * 16 + r) * DQ + q] = o;
        }
    }
}

extern "C" void kernel_launch(void* const* d_in, const int* in_sizes, int n_in,
                              void* d_out, int out_size, void* d_ws, size_t ws_size,
                              hipStream_t stream) {
    const float* x      = (const float*)d_in[0];
    const int*   ei     = (const int*)  d_in[1];
    const float* e0_w   = (const float*)d_in[2];
    const float* e0_b   = (const float*)d_in[3];
    const float* e0_g   = (const float*)d_in[4];
    const float* e0_be  = (const float*)d_in[5];
    const float* e0_m   = (const float*)d_in[6];
    const float* e0_v   = (const float*)d_in[7];
    const float* e1_w   = (const float*)d_in[8];
    const float* e1_b   = (const float*)d_in[9];
    const float* e1_g   = (const float*)d_in[10];
    const float* e1_be  = (const float*)d_in[11];
    const float* e1_m   = (const float*)d_in[12];
    const float* e1_v   = (const float*)d_in[13];
    const float* g1_w   = (const float*)d_in[14];
    const float* g1_as  = (const float*)d_in[15];
    const float* g1_ad  = (const float*)d_in[16];
    const float* g1_b   = (const float*)d_in[17];
    const float* bnc_g  = (const float*)d_in[18];
    const float* bnc_be = (const float*)d_in[19];
    const float* bnc_m  = (const float*)d_in[20];
    const float* bnc_v  = (const float*)d_in[21];
    const float* gm_w   = (const float*)d_in[22];
    const float* gm_as  = (const float*)d_in[23];
    const float* gm_ad  = (const float*)d_in[24];
    const float* gm_b   = (const float*)d_in[25];
    const float* gv_w   = (const float*)d_in[26];
    const float* gv_as  = (const float*)d_in[27];
    const float* gv_ad  = (const float*)d_in[28];
    const float* gv_b   = (const float*)d_in[29];
    const float* d0_w   = (const float*)d_in[30];
    const float* d0_b   = (const float*)d_in[31];
    const float* d0_g   = (const float*)d_in[32];
    const float* d0_be  = (const float*)d_in[33];
    const float* d0_m   = (const float*)d_in[34];
    const float* d0_v   = (const float*)d_in[35];
    const float* out_w  = (const float*)d_in[36];
    const float* out_b  = (const float*)d_in[37];
    const float* cluster= (const float*)d_in[38];
    const float* epsin  = (const float*)d_in[39];

    float* out = (float*)d_out;
    // output offsets (floats), return order: z, mu, logvar, de_feat, q, feat_x, gnn_z
    float* out_z  = out;
    float* out_mu = out + (size_t)NN * 28;
    float* out_lv = out + (size_t)NN * 36;
    float* out_de = out + (size_t)NN * 44;
    float* out_q  = out + (size_t)NN * 44 + (size_t)NN * DIN;
    float* out_fx = out + (size_t)NN * 59 + (size_t)NN * DIN;
    float* out_gz = out + (size_t)NN * 79 + (size_t)NN * DIN;

    float* ws = (float*)d_ws;
    const size_t n = NN;
    // phase-1 layout
    float* hw1   = ws;                 // 64N
    float* acc1  = ws + 64 * n;        // 64N
    float* hbuf  = ws + 128 * n;       // 32N (h, later reused as dbuf)
    float* s1src = ws + 160 * n;
    float* s1dst = ws + 161 * n;
    float* z1    = ws + 162 * n;
    // phase-2 layout (reuses hw1's 64N block after GAT1 is done)
    float* hwm   = ws;                 // 8N
    float* hwv   = ws + 8 * n;         // 8N
    float* smsrc = ws + 16 * n;
    float* smdst = ws + 17 * n;
    float* svsrc = ws + 18 * n;
    float* svdst = ws + 19 * n;
    float* zm    = ws + 20 * n;
    float* zv    = ws + 21 * n;
    float* accm  = ws + 24 * n;        // 8N
    float* accv  = ws + 32 * n;        // 8N
    float* dbuf  = hbuf;               // 32N

    const int NB_ROWS = (NN + 255) / 256;  // 157

    k_enc0<<<(NN + 255) / 256, 256, 0, stream>>>(x, e0_w, e0_b, e0_g, e0_be, e0_m, e0_v, hbuf);
    k_enc1_prep<<<NB_ROWS, 256, 0, stream>>>(hbuf, e1_w, e1_b, e1_g, e1_be, e1_m, e1_v,
                                             g1_w, g1_as, g1_ad,
                                             out_fx, hw1, s1src, s1dst, z1, acc1);
    k_gat1_acc<<<(ET * 64) / 256, 256, 0, stream>>>(ei, s1src, s1dst, hw1, z1, acc1);
    k_gat1_norm<<<NB_ROWS, 256, 0, stream>>>(acc1, z1, g1_b, bnc_g, bnc_be, bnc_m, bnc_v,
                                             gm_w, gm_as, gm_ad, gv_w, gv_as, gv_ad,
                                             hwm, hwv, smsrc, smdst, svsrc, svdst,
                                             zm, zv, accm, accv);
    k_gat23_acc<<<(ET * 8) / 256, 256, 0, stream>>>(ei, smsrc, smdst, svsrc, svdst,
                                                    hwm, hwv, zm, accm, zv, accv);
    k_final<<<NB_ROWS, 256, 0, stream>>>(accm, zm, gm_b, accv, zv, gv_b, epsin, out_fx,
                                         d0_w, d0_b, d0_g, d0_be, d0_m, d0_v, cluster,
                                         out_z, out_mu, out_lv, out_q, out_gz, dbuf);
    dim3 dec_grid((DQ + 63) / 64, NN / 64);
    k_dec_out<<<dec_grid, 256, 0, stream>>>(dbuf, out_w, out_b, out_de);
}

// Round 5
// 856.875 us; speedup vs baseline: 1.7219x; 1.1042x over previous
//
#include <hip/hip_runtime.h>
#include <cfloat>
#include <cmath>

#define NN 40000
#define DIN 3000
#define NE 640000
#define ET (NE + NN)   // edges incl. self-loops = 680000

#define BM 128        // rows per block in k_enc0
#define NCH 5         // K-chunks (split-K)
#define KCH 600       // K per chunk
#define KST 200       // K per LDS stage (3 stages/chunk)

__device__ __forceinline__ float lrelu(float x) { return x >= 0.f ? x : 0.2f * x; }
__device__ __forceinline__ float elu(float x)   { return x > 0.f ? x : expm1f(x); }

// ---------------- Kernel A: partial = x @ e0_w (split-K) ----------------
// Grid = (313 row-tiles, 5 K-chunks). Block = 256 thr = 128 rows x 32 cols;
// thread = 4 rows x 4 cols (acc[4] float4 = 16 VGPR). w slice staged in LDS
// per 200-k stage; x read as coalesced float4 with 1-step prefetch.
// Per 4-k step: 4 glb b128 + 4 lds b128 + 64 FMA.
__global__ __launch_bounds__(256, 4) void k_enc0(
    const float* __restrict__ x, const float* __restrict__ w,
    float* __restrict__ partial)   // [NCH][NN][32]
{
    __shared__ float wt[KST * 32];
    const int tid = threadIdx.x;
    const int cg = tid & 7;           // col group: 4 cols
    const int rg = tid >> 3;          // row group: 4 rows (32 groups)
    const int row0 = blockIdx.x * BM + rg * 4;
    const int chunk = blockIdx.y;
    const int kb = chunk * KCH;

    size_t xo[4];
    #pragma unroll
    for (int r = 0; r < 4; r++) {
        int rr = row0 + r; if (rr > NN - 1) rr = NN - 1;   // clamp tail
        xo[r] = (size_t)rr * DIN;
    }

    float4 acc[4];
    #pragma unroll
    for (int r = 0; r < 4; r++) acc[r] = make_float4(0.f, 0.f, 0.f, 0.f);

    for (int st = 0; st < KCH / KST; st++) {
        const int kc = kb + st * KST;
        __syncthreads();
        // stage w[kc..kc+200)[0..32): 6400 floats = 1600 float4, coalesced
        for (int i = tid; i < KST * 32 / 4; i += 256)
            ((float4*)wt)[i] = ((const float4*)(w + (size_t)kc * 32))[i];
        __syncthreads();

        float4 xv[4];
        #pragma unroll
        for (int r = 0; r < 4; r++)
            xv[r] = *(const float4*)&x[xo[r] + kc];

        for (int s = 0; s < KST / 4; s++) {
            float4 xn[4];
            if (s < KST / 4 - 1) {
                #pragma unroll
                for (int r = 0; r < 4; r++)
                    xn[r] = *(const float4*)&x[xo[r] + kc + (s + 1) * 4];
            }
            const float* wr = &wt[s * 128];
            #pragma unroll
            for (int i = 0; i < 4; i++) {
                float4 wv = *(const float4*)&wr[i * 32 + cg * 4];
                #pragma unroll
                for (int r = 0; r < 4; r++) {
                    float xs = (i == 0) ? xv[r].x : (i == 1) ? xv[r].y
                             : (i == 2) ? xv[r].z : xv[r].w;
                    acc[r].x += xs * wv.x;
                    acc[r].y += xs * wv.y;
                    acc[r].z += xs * wv.z;
                    acc[r].w += xs * wv.w;
                }
            }
            if (s < KST / 4 - 1) {
                #pragma unroll
                for (int r = 0; r < 4; r++) xv[r] = xn[r];
            }
        }
    }

    #pragma unroll
    for (int r = 0; r < 4; r++) {
        int row = row0 + r;
        if (row < NN)
            *(float4*)&partial[((size_t)chunk * NN + row) * 32 + cg * 4] = acc[r];
    }
}

// ------- Kernel A2: h = elu(bn(sum partials + e0_b)) -------
// NOTE: h aliases partial chunk 4; each thread reads its own element then
// overwrites it -> safe.
__global__ void k_enc0_fin(
    const float* __restrict__ partial,
    const float* __restrict__ b, const float* __restrict__ g,
    const float* __restrict__ beta, const float* __restrict__ m,
    const float* __restrict__ v, float* __restrict__ h)
{
    int idx = blockIdx.x * 256 + threadIdx.x;
    if (idx >= NN * 32) return;
    int c = idx & 31;
    float s = 0.f;
    #pragma unroll
    for (int ch = 0; ch < NCH; ch++)
        s += partial[(size_t)ch * NN * 32 + idx];
    float sc = g[c] * rsqrtf(v[c] + 1e-3f);
    float val = (s + b[c]) * sc + (beta[c] - m[c] * sc);
    h[idx] = elu(val);
}

// ------------- Kernel B: feat_x, hw1, attention scalars, init GAT1 atomics -------------
__global__ void k_enc1_prep(
    const float* __restrict__ h,
    const float* __restrict__ e1w, const float* __restrict__ e1b,
    const float* __restrict__ e1g, const float* __restrict__ e1beta,
    const float* __restrict__ e1m, const float* __restrict__ e1v,
    const float* __restrict__ g1w, const float* __restrict__ g1as,
    const float* __restrict__ g1ad,
    float* __restrict__ out_fx, float* __restrict__ hw1,
    float* __restrict__ s1src, float* __restrict__ s1dst,
    float* __restrict__ z1, float* __restrict__ acc1)
{
    int row = blockIdx.x * 256 + threadIdx.x;
    if (row >= NN) return;
    float hr[32];
    #pragma unroll
    for (int k = 0; k < 32; k++) hr[k] = h[(size_t)row * 32 + k];
    float fx[20];
    for (int c = 0; c < 20; c++) {
        float s = e1b[c];
        for (int k = 0; k < 32; k++) s += hr[k] * e1w[k * 20 + c];
        float sc = e1g[c] * rsqrtf(e1v[c] + 1e-3f);
        s = (s - e1m[c]) * sc + e1beta[c];
        fx[c] = elu(s);
        out_fx[(size_t)row * 20 + c] = fx[c];
    }
    float ss = 0.f, sd = 0.f;
    for (int c = 0; c < 64; c++) {
        float s = 0.f;
        for (int k = 0; k < 20; k++) s += fx[k] * g1w[k * 64 + c];
        hw1[(size_t)row * 64 + c] = s;
        ss += s * g1as[c];
        sd += s * g1ad[c];
        acc1[(size_t)row * 64 + c] = 0.f;
    }
    s1src[row] = ss; s1dst[row] = sd;
    z1[row] = 0.f;
}

// ------------- Kernel D: GAT1 numerator/denominator accumulate (64 lanes/edge) -------------
// softmax is shift-invariant: use exp(al) directly (logits bounded ~|3|), skip max pass.
__global__ __launch_bounds__(256) void k_gat1_acc(const int* __restrict__ ei,
    const float* __restrict__ s1src, const float* __restrict__ s1dst,
    const float* __restrict__ hw1,
    float* __restrict__ z1, float* __restrict__ acc1)
{
    int t = blockIdx.x * 256 + threadIdx.x;
    int lane = t & 63;
    int e = t >> 6;
    if (e >= ET) return;
    int s, d;
    if (e < NE) { s = ei[e]; d = ei[NE + e]; } else { s = d = e - NE; }
    float al = lrelu(s1src[s] + s1dst[d]);
    float ex = expf(al);
    if (lane == 0) atomicAdd(&z1[d], ex);
    atomicAdd(&acc1[(size_t)d * 64 + lane], ex * hw1[(size_t)s * 64 + lane]);
}

// ------------- Kernel E: normalize GAT1, BN+ReLU -> c; hw_m/hw_v + scalars; init atomics -------------
__global__ void k_gat1_norm(
    const float* __restrict__ acc1, const float* __restrict__ z1,
    const float* __restrict__ g1b,
    const float* __restrict__ bncg, const float* __restrict__ bncbeta,
    const float* __restrict__ bncm, const float* __restrict__ bncv,
    const float* __restrict__ gmw, const float* __restrict__ gmas, const float* __restrict__ gmad,
    const float* __restrict__ gvw, const float* __restrict__ gvas, const float* __restrict__ gvad,
    float* __restrict__ hwm, float* __restrict__ hwv,
    float* __restrict__ smsrc, float* __restrict__ smdst,
    float* __restrict__ svsrc, float* __restrict__ svdst,
    float* __restrict__ zm, float* __restrict__ zv,
    float* __restrict__ accm, float* __restrict__ accv)
{
    int row = blockIdx.x * 256 + threadIdx.x;
    if (row >= NN) return;
    float zi = 1.f / (z1[row] + 1e-16f);
    float c[64];
    for (int f = 0; f < 64; f++) {
        float val = acc1[(size_t)row * 64 + f] * zi + g1b[f];
        float sc = bncg[f] * rsqrtf(bncv[f] + 1e-5f);
        val = (val - bncm[f]) * sc + bncbeta[f];
        c[f] = val > 0.f ? val : 0.f;
    }
    float ssm = 0.f, sdm = 0.f, ssv = 0.f, sdv = 0.f;
    for (int o = 0; o < 8; o++) {
        float sm = 0.f, sv = 0.f;
        for (int k = 0; k < 64; k++) {
            sm += c[k] * gmw[k * 8 + o];
            sv += c[k] * gvw[k * 8 + o];
        }
        hwm[(size_t)row * 8 + o] = sm; hwv[(size_t)row * 8 + o] = sv;
        ssm += sm * gmas[o]; sdm += sm * gmad[o];
        ssv += sv * gvas[o]; sdv += sv * gvad[o];
        accm[(size_t)row * 8 + o] = 0.f; accv[(size_t)row * 8 + o] = 0.f;
    }
    smsrc[row] = ssm; smdst[row] = sdm;
    svsrc[row] = ssv; svdst[row] = sdv;
    zm[row] = 0.f;
    zv[row] = 0.f;
}

// ------------- Kernel G: mu/logvar GAT accumulate (8 lanes/edge), no max pass -------------
__global__ __launch_bounds__(256) void k_gat23_acc(const int* __restrict__ ei,
    const float* __restrict__ smsrc, const float* __restrict__ smdst,
    const float* __restrict__ svsrc, const float* __restrict__ svdst,
    const float* __restrict__ hwm, const float* __restrict__ hwv,
    float* __restrict__ zm, float* __restrict__ accm,
    float* __restrict__ zv, float* __restrict__ accv)
{
    int t = blockIdx.x * 256 + threadIdx.x;
    int lane = t & 7;
    int e = t >> 3;
    if (e >= ET) return;
    int s, d;
    if (e < NE) { s = ei[e]; d = ei[NE + e]; } else { s = d = e - NE; }
    float am = lrelu(smsrc[s] + smdst[d]);
    float exm = expf(am);
    if (lane == 0) atomicAdd(&zm[d], exm);
    atomicAdd(&accm[(size_t)d * 8 + lane], exm * hwm[(size_t)s * 8 + lane]);
    float av = lrelu(svsrc[s] + svdst[d]);
    float exv = expf(av);
    if (lane == 0) atomicAdd(&zv[d], exv);
    atomicAdd(&accv[(size_t)d * 8 + lane], exv * hwv[(size_t)s * 8 + lane]);
}

// ------------- Kernel H: mu/logvar/gnn_z/z, decoder L0, student-t q -------------
__global__ void k_final(
    const float* __restrict__ accm, const float* __restrict__ zm, const float* __restrict__ gmb,
    const float* __restrict__ accv, const float* __restrict__ zv, const float* __restrict__ gvb,
    const float* __restrict__ epsin, const float* __restrict__ fx_out,
    const float* __restrict__ d0w, const float* __restrict__ d0b,
    const float* __restrict__ d0g, const float* __restrict__ d0beta,
    const float* __restrict__ d0m, const float* __restrict__ d0v,
    const float* __restrict__ cluster,
    float* __restrict__ out_z, float* __restrict__ out_mu, float* __restrict__ out_lv,
    float* __restrict__ out_q, float* __restrict__ out_gz, float* __restrict__ dbuf)
{
    int row = blockIdx.x * 256 + threadIdx.x;
    if (row >= NN) return;
    float zvec[28];
    #pragma unroll
    for (int k = 0; k < 20; k++) zvec[k] = fx_out[(size_t)row * 20 + k];
    float zim = 1.f / (zm[row] + 1e-16f);
    float ziv = 1.f / (zv[row] + 1e-16f);
    #pragma unroll
    for (int o = 0; o < 8; o++) {
        float mu = accm[(size_t)row * 8 + o] * zim + gmb[o];
        float lv = accv[(size_t)row * 8 + o] * ziv + gvb[o];
        float gz = epsin[(size_t)row * 8 + o] * expf(lv) + mu;
        out_mu[(size_t)row * 8 + o] = mu;
        out_lv[(size_t)row * 8 + o] = lv;
        out_gz[(size_t)row * 8 + o] = gz;
        zvec[20 + o] = gz;
    }
    #pragma unroll
    for (int k = 0; k < 28; k++) out_z[(size_t)row * 28 + k] = zvec[k];
    // decoder L0: elu(bn(z @ d0_w + d0_b))
    for (int c = 0; c < 32; c++) {
        float s = d0b[c];
        for (int k = 0; k < 28; k++) s += zvec[k] * d0w[k * 32 + c];
        float sc = d0g[c] * rsqrtf(d0v[c] + 1e-3f);
        s = (s - d0m[c]) * sc + d0beta[c];
        dbuf[(size_t)row * 32 + c] = elu(s);
    }
    // student-t q
    float zz = 0.f;
    #pragma unroll
    for (int k = 0; k < 28; k++) zz += zvec[k] * zvec[k];
    float qv[15], qs = 0.f;
    for (int j = 0; j < 15; j++) {
        float cc = 0.f, zc = 0.f;
        for (int k = 0; k < 28; k++) {
            float cv = cluster[j * 28 + k];
            cc += cv * cv; zc += zvec[k] * cv;
        }
        float sq = zz + cc - 2.f * zc;
        if (sq < 0.f) sq = 0.f;
        float qb = 1.f / (1.f + sq * (1.f / 0.9f) + 1e-8f);
        qb = powf(qb, 0.95f);
        qv[j] = qb; qs += qb;
    }
    float qi = 1.f / qs;
    #pragma unroll
    for (int j = 0; j < 15; j++) out_q[(size_t)row * 15 + j] = qv[j] * qi;
}

// ------------- Kernel I: de_feat = d @ out_w + out_b -------------
// Tiled: 64 rows x 256 cols per block. LDS: w tile [32][256] (32KB) + d tile
// [64][32] (8KB). Thread = 16 rows x 4 cols (float4). float4 loads/stores.
#define DQ 750   // DIN/4 quads per row
__global__ __launch_bounds__(256) void k_dec_out(
    const float* __restrict__ dbuf, const float* __restrict__ ow,
    const float* __restrict__ ob, float* __restrict__ out_de)
{
    __shared__ float4 wt[32 * 64];   // [k][quad]
    __shared__ float  dt[64 * 32];   // [row][k]
    const int tid = threadIdx.x;
    const int cq0 = blockIdx.x * 64;      // quad base in output row
    const int row0 = blockIdx.y * 64;

    // load w tile: 32 k-rows x 64 quads
    #pragma unroll
    for (int i = 0; i < 8; i++) {
        int t = tid + i * 256;            // 0..2047
        int k = t >> 6, lq = t & 63;
        int gq = cq0 + lq;
        wt[t] = (gq < DQ) ? ((const float4*)ow)[(size_t)k * DQ + gq]
                          : make_float4(0.f, 0.f, 0.f, 0.f);
    }
    // load d tile: 64 rows x 32 = 512 float4
    #pragma unroll
    for (int i = 0; i < 2; i++) {
        int t = tid + i * 256;
        ((float4*)dt)[t] = ((const float4*)dbuf)[(size_t)row0 * 8 + t];
    }
    __syncthreads();

    const int qid = tid & 63;
    const int rg  = tid >> 6;             // wave-uniform row group (0..3)
    const int q   = cq0 + qid;
    const bool valid = q < DQ;

    float4 acc[16];
    #pragma unroll
    for (int r = 0; r < 16; r++) acc[r] = make_float4(0.f, 0.f, 0.f, 0.f);

    #pragma unroll
    for (int k4 = 0; k4 < 8; k4++) {
        float4 w0 = wt[(k4 * 4 + 0) * 64 + qid];
        float4 w1 = wt[(k4 * 4 + 1) * 64 + qid];
        float4 w2 = wt[(k4 * 4 + 2) * 64 + qid];
        float4 w3 = wt[(k4 * 4 + 3) * 64 + qid];
        #pragma unroll
        for (int r = 0; r < 16; r++) {
            float4 dq = *(const float4*)&dt[(rg * 16 + r) * 32 + k4 * 4]; // broadcast
            acc[r].x += dq.x * w0.x; acc[r].y += dq.x * w0.y;
            acc[r].z += dq.x * w0.z; acc[r].w += dq.x * w0.w;
            acc[r].x += dq.y * w1.x; acc[r].y += dq.y * w1.y;
            acc[r].z += dq.y * w1.z; acc[r].w += dq.y * w1.w;
            acc[r].x += dq.z * w2.x; acc[r].y += dq.z * w2.y;
            acc[r].z += dq.z * w2.z; acc[r].w += dq.z * w2.w;
            acc[r].x += dq.w * w3.x; acc[r].y += dq.w * w3.y;
            acc[r].z += dq.w * w3.z; acc[r].w += dq.w * w3.w;
        }
    }

    if (valid) {
        float4 bq = ((const float4*)ob)[q];
        #pragma unroll
        for (int r = 0; r < 16; r++) {
            float4 o;
            o.x = acc[r].x + bq.x; o.y = acc[r].y + bq.y;
            o.z = acc[r].z + bq.z; o.w = acc[r].w + bq.w;
            ((float4*)out_de)[(size_t)(row0 + rg * 16 + r) * DQ + q] = o;
        }
    }
}

extern "C" void kernel_launch(void* const* d_in, const int* in_sizes, int n_in,
                              void* d_out, int out_size, void* d_ws, size_t ws_size,
                              hipStream_t stream) {
    const float* x      = (const float*)d_in[0];
    const int*   ei     = (const int*)  d_in[1];
    const float* e0_w   = (const float*)d_in[2];
    const float* e0_b   = (const float*)d_in[3];
    const float* e0_g   = (const float*)d_in[4];
    const float* e0_be  = (const float*)d_in[5];
    const float* e0_m   = (const float*)d_in[6];
    const float* e0_v   = (const float*)d_in[7];
    const float* e1_w   = (const float*)d_in[8];
    const float* e1_b   = (const float*)d_in[9];
    const float* e1_g   = (const float*)d_in[10];
    const float* e1_be  = (const float*)d_in[11];
    const float* e1_m   = (const float*)d_in[12];
    const float* e1_v   = (const float*)d_in[13];
    const float* g1_w   = (const float*)d_in[14];
    const float* g1_as  = (const float*)d_in[15];
    const float* g1_ad  = (const float*)d_in[16];
    const float* g1_b   = (const float*)d_in[17];
    const float* bnc_g  = (const float*)d_in[18];
    const float* bnc_be = (const float*)d_in[19];
    const float* bnc_m  = (const float*)d_in[20];
    const float* bnc_v  = (const float*)d_in[21];
    const float* gm_w   = (const float*)d_in[22];
    const float* gm_as  = (const float*)d_in[23];
    const float* gm_ad  = (const float*)d_in[24];
    const float* gm_b   = (const float*)d_in[25];
    const float* gv_w   = (const float*)d_in[26];
    const float* gv_as  = (const float*)d_in[27];
    const float* gv_ad  = (const float*)d_in[28];
    const float* gv_b   = (const float*)d_in[29];
    const float* d0_w   = (const float*)d_in[30];
    const float* d0_b   = (const float*)d_in[31];
    const float* d0_g   = (const float*)d_in[32];
    const float* d0_be  = (const float*)d_in[33];
    const float* d0_m   = (const float*)d_in[34];
    const float* d0_v   = (const float*)d_in[35];
    const float* out_w  = (const float*)d_in[36];
    const float* out_b  = (const float*)d_in[37];
    const float* cluster= (const float*)d_in[38];
    const float* epsin  = (const float*)d_in[39];

    float* out = (float*)d_out;
    // output offsets (floats), return order: z, mu, logvar, de_feat, q, feat_x, gnn_z
    float* out_z  = out;
    float* out_mu = out + (size_t)NN * 28;
    float* out_lv = out + (size_t)NN * 36;
    float* out_de = out + (size_t)NN * 44;
    float* out_q  = out + (size_t)NN * 44 + (size_t)NN * DIN;
    float* out_fx = out + (size_t)NN * 59 + (size_t)NN * DIN;
    float* out_gz = out + (size_t)NN * 79 + (size_t)NN * DIN;

    float* ws = (float*)d_ws;
    const size_t n = NN;
    // enc0 phase: partial[5][N][32] = ws[0..160N); chunk-4 slice aliases hbuf.
    float* partial = ws;
    // phase-1 layout
    float* hw1   = ws;                 // 64N
    float* acc1  = ws + 64 * n;        // 64N
    float* hbuf  = ws + 128 * n;       // 32N (h, later reused as dbuf)
    float* s1src = ws + 160 * n;
    float* s1dst = ws + 161 * n;
    float* z1    = ws + 162 * n;
    // phase-2 layout (reuses hw1's 64N block after GAT1 is done)
    float* hwm   = ws;                 // 8N
    float* hwv   = ws + 8 * n;         // 8N
    float* smsrc = ws + 16 * n;
    float* smdst = ws + 17 * n;
    float* svsrc = ws + 18 * n;
    float* svdst = ws + 19 * n;
    float* zm    = ws + 20 * n;
    float* zv    = ws + 21 * n;
    float* accm  = ws + 24 * n;        // 8N
    float* accv  = ws + 32 * n;        // 8N
    float* dbuf  = hbuf;               // 32N

    const int NB_ROWS = (NN + 255) / 256;  // 157

    dim3 enc0_grid((NN + BM - 1) / BM, NCH);   // 313 x 5
    k_enc0<<<enc0_grid, 256, 0, stream>>>(x, e0_w, partial);
    k_enc0_fin<<<(NN * 32 + 255) / 256, 256, 0, stream>>>(partial, e0_b, e0_g, e0_be,
                                                          e0_m, e0_v, hbuf);
    k_enc1_prep<<<NB_ROWS, 256, 0, stream>>>(hbuf, e1_w, e1_b, e1_g, e1_be, e1_m, e1_v,
                                             g1_w, g1_as, g1_ad,
                                             out_fx, hw1, s1src, s1dst, z1, acc1);
    k_gat1_acc<<<(ET * 64) / 256, 256, 0, stream>>>(ei, s1src, s1dst, hw1, z1, acc1);
    k_gat1_norm<<<NB_ROWS, 256, 0, stream>>>(acc1, z1, g1_b, bnc_g, bnc_be, bnc_m, bnc_v,
                                             gm_w, gm_as, gm_ad, gv_w, gv_as, gv_ad,
                                             hwm, hwv, smsrc, smdst, svsrc, svdst,
                                             zm, zv, accm, accv);
    k_gat23_acc<<<(ET * 8) / 256, 256, 0, stream>>>(ei, smsrc, smdst, svsrc, svdst,
                                                    hwm, hwv, zm, accm, zv, accv);
    k_final<<<NB_ROWS, 256, 0, stream>>>(accm, zm, gm_b, accv, zv, gv_b, epsin, out_fx,
                                         d0_w, d0_b, d0_g, d0_be, d0_m, d0_v, cluster,
                                         out_z, out_mu, out_lv, out_q, out_gz, dbuf);
    dim3 dec_grid((DQ + 63) / 64, NN / 64);
    k_dec_out<<<dec_grid, 256, 0, stream>>>(dbuf, out_w, out_b, out_de);
}

// Round 6
// 845.938 us; speedup vs baseline: 1.7442x; 1.0129x over previous
//
#include <hip/hip_runtime.h>
#include <cfloat>
#include <cmath>

#define NN 40000
#define DIN 3000
#define NE 640000
#define ET (NE + NN)   // edges incl. self-loops = 680000

#define ROWS 64       // rows per block in k_enc0
#define KC 100        // K per LDS stage
#define SX 104        // padded x-tile stride (104%32=8 -> 2-way alias, free)
#define KSPLIT 1500   // K per split-K chunk (2 chunks)

__device__ __forceinline__ float lrelu(float x) { return x >= 0.f ? x : 0.2f * x; }
__device__ __forceinline__ float elu(float x)   { return x > 0.f ? x : expm1f(x); }

// ---------------- Kernel A: partial = x @ e0_w (split-K x2, LDS-staged) ----------------
// Block 256 thr = 64 rows x 32 cols tile; thread = 2 rows x 4 cols (acc 8 VGPR).
// x tile [64][100] staged coalesced (1KB/wave-instr), w slice contiguous.
// Per 4-k step: 2 x-b128 + 4 w-b128 LDS + 32 FMA.
__global__ __launch_bounds__(256) void k_enc0(
    const float* __restrict__ x, const float* __restrict__ w,
    float* __restrict__ partial)   // [2][NN][32]
{
    __shared__ float xt[ROWS * SX];   // 26.6 KB
    __shared__ float wt[KC * 32];     // 12.8 KB
    const int tid = threadIdx.x;
    const int cg = tid & 7;           // col group (4 cols)
    const int rg = tid >> 3;          // 0..31; rows rg and rg+32
    const int row0 = blockIdx.x * ROWS;
    const int kb = blockIdx.y * KSPLIT;

    float4 acc0 = make_float4(0.f, 0.f, 0.f, 0.f);
    float4 acc1 = make_float4(0.f, 0.f, 0.f, 0.f);

    for (int ch = 0; ch < KSPLIT / KC; ch++) {
        const int kc = kb + ch * KC;
        __syncthreads();
        // stage x: 64 rows x 100 floats = 1600 float4, coalesced per row
        for (int j = tid; j < 1600; j += 256) {
            int r = j / 25, q = j - r * 25;
            float4 v = *(const float4*)&x[(size_t)(row0 + r) * DIN + kc + q * 4];
            *(float4*)&xt[r * SX + q * 4] = v;
        }
        // stage w slice [kc..kc+100)[0..32): contiguous 800 float4
        for (int j = tid; j < 800; j += 256)
            ((float4*)wt)[j] = ((const float4*)&w[(size_t)kc * 32])[j];
        __syncthreads();

        for (int s = 0; s < 25; s++) {
            float4 xa = *(const float4*)&xt[rg * SX + s * 4];
            float4 xb = *(const float4*)&xt[(rg + 32) * SX + s * 4];
            #pragma unroll
            for (int i = 0; i < 4; i++) {
                float4 wv = *(const float4*)&wt[(s * 4 + i) * 32 + cg * 4];
                float a = (i == 0) ? xa.x : (i == 1) ? xa.y : (i == 2) ? xa.z : xa.w;
                float b = (i == 0) ? xb.x : (i == 1) ? xb.y : (i == 2) ? xb.z : xb.w;
                acc0.x += a * wv.x; acc0.y += a * wv.y;
                acc0.z += a * wv.z; acc0.w += a * wv.w;
                acc1.x += b * wv.x; acc1.y += b * wv.y;
                acc1.z += b * wv.z; acc1.w += b * wv.w;
            }
        }
    }

    *(float4*)&partial[((size_t)blockIdx.y * NN + row0 + rg) * 32 + cg * 4] = acc0;
    *(float4*)&partial[((size_t)blockIdx.y * NN + row0 + rg + 32) * 32 + cg * 4] = acc1;
}

// ------- Kernel A2: h = elu(bn(partial0 + partial1 + e0_b)) -------
__global__ void k_enc0_fin(
    const float* __restrict__ partial,
    const float* __restrict__ b, const float* __restrict__ g,
    const float* __restrict__ beta, const float* __restrict__ m,
    const float* __restrict__ v, float* __restrict__ h)
{
    int idx = blockIdx.x * 256 + threadIdx.x;
    if (idx >= NN * 32) return;
    int c = idx & 31;
    float s = partial[idx] + partial[(size_t)NN * 32 + idx];
    float sc = g[c] * rsqrtf(v[c] + 1e-3f);
    float val = (s + b[c]) * sc + (beta[c] - m[c] * sc);
    h[idx] = elu(val);
}

// ------------- Kernel B: feat_x, hw1, attention scalars, init GAT1 atomics -------------
__global__ void k_enc1_prep(
    const float* __restrict__ h,
    const float* __restrict__ e1w, const float* __restrict__ e1b,
    const float* __restrict__ e1g, const float* __restrict__ e1beta,
    const float* __restrict__ e1m, const float* __restrict__ e1v,
    const float* __restrict__ g1w, const float* __restrict__ g1as,
    const float* __restrict__ g1ad,
    float* __restrict__ out_fx, float* __restrict__ hw1,
    float* __restrict__ s1src, float* __restrict__ s1dst,
    float* __restrict__ z1, float* __restrict__ acc1)
{
    int row = blockIdx.x * 256 + threadIdx.x;
    if (row >= NN) return;
    float hr[32];
    #pragma unroll
    for (int k = 0; k < 32; k++) hr[k] = h[(size_t)row * 32 + k];
    float fx[20];
    for (int c = 0; c < 20; c++) {
        float s = e1b[c];
        for (int k = 0; k < 32; k++) s += hr[k] * e1w[k * 20 + c];
        float sc = e1g[c] * rsqrtf(e1v[c] + 1e-3f);
        s = (s - e1m[c]) * sc + e1beta[c];
        fx[c] = elu(s);
        out_fx[(size_t)row * 20 + c] = fx[c];
    }
    float ss = 0.f, sd = 0.f;
    for (int c = 0; c < 64; c++) {
        float s = 0.f;
        for (int k = 0; k < 20; k++) s += fx[k] * g1w[k * 64 + c];
        hw1[(size_t)row * 64 + c] = s;
        ss += s * g1as[c];
        sd += s * g1ad[c];
        acc1[(size_t)row * 64 + c] = 0.f;
    }
    s1src[row] = ss; s1dst[row] = sd;
    z1[row] = 0.f;
}

// ------------- Kernel D: GAT1 numerator/denominator accumulate (64 lanes/edge) -------------
// softmax is shift-invariant: use exp(al) directly (logits bounded ~|3|), skip max pass.
__global__ __launch_bounds__(256) void k_gat1_acc(const int* __restrict__ ei,
    const float* __restrict__ s1src, const float* __restrict__ s1dst,
    const float* __restrict__ hw1,
    float* __restrict__ z1, float* __restrict__ acc1)
{
    int t = blockIdx.x * 256 + threadIdx.x;
    int lane = t & 63;
    int e = t >> 6;
    if (e >= ET) return;
    int s, d;
    if (e < NE) { s = ei[e]; d = ei[NE + e]; } else { s = d = e - NE; }
    float al = lrelu(s1src[s] + s1dst[d]);
    float ex = expf(al);
    if (lane == 0) atomicAdd(&z1[d], ex);
    atomicAdd(&acc1[(size_t)d * 64 + lane], ex * hw1[(size_t)s * 64 + lane]);
}

// ------------- Kernel E: normalize GAT1, BN+ReLU -> c; hw_m/hw_v + scalars; init atomics -------------
__global__ void k_gat1_norm(
    const float* __restrict__ acc1, const float* __restrict__ z1,
    const float* __restrict__ g1b,
    const float* __restrict__ bncg, const float* __restrict__ bncbeta,
    const float* __restrict__ bncm, const float* __restrict__ bncv,
    const float* __restrict__ gmw, const float* __restrict__ gmas, const float* __restrict__ gmad,
    const float* __restrict__ gvw, const float* __restrict__ gvas, const float* __restrict__ gvad,
    float* __restrict__ hwm, float* __restrict__ hwv,
    float* __restrict__ smsrc, float* __restrict__ smdst,
    float* __restrict__ svsrc, float* __restrict__ svdst,
    float* __restrict__ zm, float* __restrict__ zv,
    float* __restrict__ accm, float* __restrict__ accv)
{
    int row = blockIdx.x * 256 + threadIdx.x;
    if (row >= NN) return;
    float zi = 1.f / (z1[row] + 1e-16f);
    float c[64];
    for (int f = 0; f < 64; f++) {
        float val = acc1[(size_t)row * 64 + f] * zi + g1b[f];
        float sc = bncg[f] * rsqrtf(bncv[f] + 1e-5f);
        val = (val - bncm[f]) * sc + bncbeta[f];
        c[f] = val > 0.f ? val : 0.f;
    }
    float ssm = 0.f, sdm = 0.f, ssv = 0.f, sdv = 0.f;
    for (int o = 0; o < 8; o++) {
        float sm = 0.f, sv = 0.f;
        for (int k = 0; k < 64; k++) {
            sm += c[k] * gmw[k * 8 + o];
            sv += c[k] * gvw[k * 8 + o];
        }
        hwm[(size_t)row * 8 + o] = sm; hwv[(size_t)row * 8 + o] = sv;
        ssm += sm * gmas[o]; sdm += sm * gmad[o];
        ssv += sv * gvas[o]; sdv += sv * gvad[o];
        accm[(size_t)row * 8 + o] = 0.f; accv[(size_t)row * 8 + o] = 0.f;
    }
    smsrc[row] = ssm; smdst[row] = sdm;
    svsrc[row] = ssv; svdst[row] = sdv;
    zm[row] = 0.f;
    zv[row] = 0.f;
}

// ------------- Kernel G: mu/logvar GAT accumulate (8 lanes/edge), no max pass -------------
__global__ __launch_bounds__(256) void k_gat23_acc(const int* __restrict__ ei,
    const float* __restrict__ smsrc, const float* __restrict__ smdst,
    const float* __restrict__ svsrc, const float* __restrict__ svdst,
    const float* __restrict__ hwm, const float* __restrict__ hwv,
    float* __restrict__ zm, float* __restrict__ accm,
    float* __restrict__ zv, float* __restrict__ accv)
{
    int t = blockIdx.x * 256 + threadIdx.x;
    int lane = t & 7;
    int e = t >> 3;
    if (e >= ET) return;
    int s, d;
    if (e < NE) { s = ei[e]; d = ei[NE + e]; } else { s = d = e - NE; }
    float am = lrelu(smsrc[s] + smdst[d]);
    float exm = expf(am);
    if (lane == 0) atomicAdd(&zm[d], exm);
    atomicAdd(&accm[(size_t)d * 8 + lane], exm * hwm[(size_t)s * 8 + lane]);
    float av = lrelu(svsrc[s] + svdst[d]);
    float exv = expf(av);
    if (lane == 0) atomicAdd(&zv[d], exv);
    atomicAdd(&accv[(size_t)d * 8 + lane], exv * hwv[(size_t)s * 8 + lane]);
}

// ------------- Kernel H: mu/logvar/gnn_z/z, decoder L0, student-t q -------------
__global__ void k_final(
    const float* __restrict__ accm, const float* __restrict__ zm, const float* __restrict__ gmb,
    const float* __restrict__ accv, const float* __restrict__ zv, const float* __restrict__ gvb,
    const float* __restrict__ epsin, const float* __restrict__ fx_out,
    const float* __restrict__ d0w, const float* __restrict__ d0b,
    const float* __restrict__ d0g, const float* __restrict__ d0beta,
    const float* __restrict__ d0m, const float* __restrict__ d0v,
    const float* __restrict__ cluster,
    float* __restrict__ out_z, float* __restrict__ out_mu, float* __restrict__ out_lv,
    float* __restrict__ out_q, float* __restrict__ out_gz, float* __restrict__ dbuf)
{
    int row = blockIdx.x * 256 + threadIdx.x;
    if (row >= NN) return;
    float zvec[28];
    #pragma unroll
    for (int k = 0; k < 20; k++) zvec[k] = fx_out[(size_t)row * 20 + k];
    float zim = 1.f / (zm[row] + 1e-16f);
    float ziv = 1.f / (zv[row] + 1e-16f);
    #pragma unroll
    for (int o = 0; o < 8; o++) {
        float mu = accm[(size_t)row * 8 + o] * zim + gmb[o];
        float lv = accv[(size_t)row * 8 + o] * ziv + gvb[o];
        float gz = epsin[(size_t)row * 8 + o] * expf(lv) + mu;
        out_mu[(size_t)row * 8 + o] = mu;
        out_lv[(size_t)row * 8 + o] = lv;
        out_gz[(size_t)row * 8 + o] = gz;
        zvec[20 + o] = gz;
    }
    #pragma unroll
    for (int k = 0; k < 28; k++) out_z[(size_t)row * 28 + k] = zvec[k];
    // decoder L0: elu(bn(z @ d0_w + d0_b))
    for (int c = 0; c < 32; c++) {
        float s = d0b[c];
        for (int k = 0; k < 28; k++) s += zvec[k] * d0w[k * 32 + c];
        float sc = d0g[c] * rsqrtf(d0v[c] + 1e-3f);
        s = (s - d0m[c]) * sc + d0beta[c];
        dbuf[(size_t)row * 32 + c] = elu(s);
    }
    // student-t q
    float zz = 0.f;
    #pragma unroll
    for (int k = 0; k < 28; k++) zz += zvec[k] * zvec[k];
    float qv[15], qs = 0.f;
    for (int j = 0; j < 15; j++) {
        float cc = 0.f, zc = 0.f;
        for (int k = 0; k < 28; k++) {
            float cv = cluster[j * 28 + k];
            cc += cv * cv; zc += zvec[k] * cv;
        }
        float sq = zz + cc - 2.f * zc;
        if (sq < 0.f) sq = 0.f;
        float qb = 1.f / (1.f + sq * (1.f / 0.9f) + 1e-8f);
        qb = powf(qb, 0.95f);
        qv[j] = qb; qs += qb;
    }
    float qi = 1.f / qs;
    #pragma unroll
    for (int j = 0; j < 15; j++) out_q[(size_t)row * 15 + j] = qv[j] * qi;
}

// ------------- Kernel I: de_feat = d @ out_w + out_b -------------
#define DQ 750   // DIN/4 quads per row
__global__ __launch_bounds__(256) void k_dec_out(
    const float* __restrict__ dbuf, const float* __restrict__ ow,
    const float* __restrict__ ob, float* __restrict__ out_de)
{
    __shared__ float4 wt[32 * 64];   // [k][quad]
    __shared__ float  dt[64 * 32];   // [row][k]
    const int tid = threadIdx.x;
    const int cq0 = blockIdx.x * 64;      // quad base in output row
    const int row0 = blockIdx.y * 64;

    // load w tile: 32 k-rows x 64 quads
    #pragma unroll
    for (int i = 0; i < 8; i++) {
        int t = tid + i * 256;            // 0..2047
        int k = t >> 6, lq = t & 63;
        int gq = cq0 + lq;
        wt[t] = (gq < DQ) ? ((const float4*)ow)[(size_t)k * DQ + gq]
                          : make_float4(0.f, 0.f, 0.f, 0.f);
    }
    // load d tile: 64 rows x 32 = 512 float4
    #pragma unroll
    for (int i = 0; i < 2; i++) {
        int t = tid + i * 256;
        ((float4*)dt)[t] = ((const float4*)dbuf)[(size_t)row0 * 8 + t];
    }
    __syncthreads();

    const int qid = tid & 63;
    const int rg  = tid >> 6;             // wave-uniform row group (0..3)
    const int q   = cq0 + qid;
    const bool valid = q < DQ;

    float4 acc[16];
    #pragma unroll
    for (int r = 0; r < 16; r++) acc[r] = make_float4(0.f, 0.f, 0.f, 0.f);

    #pragma unroll
    for (int k4 = 0; k4 < 8; k4++) {
        float4 w0 = wt[(k4 * 4 + 0) * 64 + qid];
        float4 w1 = wt[(k4 * 4 + 1) * 64 + qid];
        float4 w2 = wt[(k4 * 4 + 2) * 64 + qid];
        float4 w3 = wt[(k4 * 4 + 3) * 64 + qid];
        #pragma unroll
        for (int r = 0; r < 16; r++) {
            float4 dq = *(const float4*)&dt[(rg * 16 + r) * 32 + k4 * 4]; // broadcast
            acc[r].x += dq.x * w0.x; acc[r].y += dq.x * w0.y;
            acc[r].z += dq.x * w0.z; acc[r].w += dq.x * w0.w;
            acc[r].x += dq.y * w1.x; acc[r].y += dq.y * w1.y;
            acc[r].z += dq.y * w1.z; acc[r].w += dq.y * w1.w;
            acc[r].x += dq.z * w2.x; acc[r].y += dq.z * w2.y;
            acc[r].z += dq.z * w2.z; acc[r].w += dq.z * w2.w;
            acc[r].x += dq.w * w3.x; acc[r].y += dq.w * w3.y;
            acc[r].z += dq.w * w3.z; acc[r].w += dq.w * w3.w;
        }
    }

    if (valid) {
        float4 bq = ((const float4*)ob)[q];
        #pragma unroll
        for (int r = 0; r < 16; r++) {
            float4 o;
            o.x = acc[r].x + bq.x; o.y = acc[r].y + bq.y;
            o.z = acc[r].z + bq.z; o.w = acc[r].w + bq.w;
            ((float4*)out_de)[(size_t)(row0 + rg * 16 + r) * DQ + q] = o;
        }
    }
}

extern "C" void kernel_launch(void* const* d_in, const int* in_sizes, int n_in,
                              void* d_out, int out_size, void* d_ws, size_t ws_size,
                              hipStream_t stream) {
    const float* x      = (const float*)d_in[0];
    const int*   ei     = (const int*)  d_in[1];
    const float* e0_w   = (const float*)d_in[2];
    const float* e0_b   = (const float*)d_in[3];
    const float* e0_g   = (const float*)d_in[4];
    const float* e0_be  = (const float*)d_in[5];
    const float* e0_m   = (const float*)d_in[6];
    const float* e0_v   = (const float*)d_in[7];
    const float* e1_w   = (const float*)d_in[8];
    const float* e1_b   = (const float*)d_in[9];
    const float* e1_g   = (const float*)d_in[10];
    const float* e1_be  = (const float*)d_in[11];
    const float* e1_m   = (const float*)d_in[12];
    const float* e1_v   = (const float*)d_in[13];
    const float* g1_w   = (const float*)d_in[14];
    const float* g1_as  = (const float*)d_in[15];
    const float* g1_ad  = (const float*)d_in[16];
    const float* g1_b   = (const float*)d_in[17];
    const float* bnc_g  = (const float*)d_in[18];
    const float* bnc_be = (const float*)d_in[19];
    const float* bnc_m  = (const float*)d_in[20];
    const float* bnc_v  = (const float*)d_in[21];
    const float* gm_w   = (const float*)d_in[22];
    const float* gm_as  = (const float*)d_in[23];
    const float* gm_ad  = (const float*)d_in[24];
    const float* gm_b   = (const float*)d_in[25];
    const float* gv_w   = (const float*)d_in[26];
    const float* gv_as  = (const float*)d_in[27];
    const float* gv_ad  = (const float*)d_in[28];
    const float* gv_b   = (const float*)d_in[29];
    const float* d0_w   = (const float*)d_in[30];
    const float* d0_b   = (const float*)d_in[31];
    const float* d0_g   = (const float*)d_in[32];
    const float* d0_be  = (const float*)d_in[33];
    const float* d0_m   = (const float*)d_in[34];
    const float* d0_v   = (const float*)d_in[35];
    const float* out_w  = (const float*)d_in[36];
    const float* out_b  = (const float*)d_in[37];
    const float* cluster= (const float*)d_in[38];
    const float* epsin  = (const float*)d_in[39];

    float* out = (float*)d_out;
    // output offsets (floats), return order: z, mu, logvar, de_feat, q, feat_x, gnn_z
    float* out_z  = out;
    float* out_mu = out + (size_t)NN * 28;
    float* out_lv = out + (size_t)NN * 36;
    float* out_de = out + (size_t)NN * 44;
    float* out_q  = out + (size_t)NN * 44 + (size_t)NN * DIN;
    float* out_fx = out + (size_t)NN * 59 + (size_t)NN * DIN;
    float* out_gz = out + (size_t)NN * 79 + (size_t)NN * DIN;

    float* ws = (float*)d_ws;
    const size_t n = NN;
    // enc0 phase: partial[2][N][32] = ws[0..64N) (aliases hw1 region, used later)
    float* partial = ws;
    // phase-1 layout
    float* hw1   = ws;                 // 64N
    float* acc1  = ws + 64 * n;        // 64N
    float* hbuf  = ws + 128 * n;       // 32N (h, later reused as dbuf)
    float* s1src = ws + 160 * n;
    float* s1dst = ws + 161 * n;
    float* z1    = ws + 162 * n;
    // phase-2 layout (reuses hw1's 64N block after GAT1 is done)
    float* hwm   = ws;                 // 8N
    float* hwv   = ws + 8 * n;         // 8N
    float* smsrc = ws + 16 * n;
    float* smdst = ws + 17 * n;
    float* svsrc = ws + 18 * n;
    float* svdst = ws + 19 * n;
    float* zm    = ws + 20 * n;
    float* zv    = ws + 21 * n;
    float* accm  = ws + 24 * n;        // 8N
    float* accv  = ws + 32 * n;        // 8N
    float* dbuf  = hbuf;               // 32N

    const int NB_ROWS = (NN + 255) / 256;  // 157

    dim3 enc0_grid(NN / ROWS, 2);   // 625 x 2
    k_enc0<<<enc0_grid, 256, 0, stream>>>(x, e0_w, partial);
    k_enc0_fin<<<(NN * 32 + 255) / 256, 256, 0, stream>>>(partial, e0_b, e0_g, e0_be,
                                                          e0_m, e0_v, hbuf);
    k_enc1_prep<<<NB_ROWS, 256, 0, stream>>>(hbuf, e1_w, e1_b, e1_g, e1_be, e1_m, e1_v,
                                             g1_w, g1_as, g1_ad,
                                             out_fx, hw1, s1src, s1dst, z1, acc1);
    k_gat1_acc<<<(ET * 64) / 256, 256, 0, stream>>>(ei, s1src, s1dst, hw1, z1, acc1);
    k_gat1_norm<<<NB_ROWS, 256, 0, stream>>>(acc1, z1, g1_b, bnc_g, bnc_be, bnc_m, bnc_v,
                                             gm_w, gm_as, gm_ad, gv_w, gv_as, gv_ad,
                                             hwm, hwv, smsrc, smdst, svsrc, svdst,
                                             zm, zv, accm, accv);
    k_gat23_acc<<<(ET * 8) / 256, 256, 0, stream>>>(ei, smsrc, smdst, svsrc, svdst,
                                                    hwm, hwv, zm, accm, zv, accv);
    k_final<<<NB_ROWS, 256, 0, stream>>>(accm, zm, gm_b, accv, zv, gv_b, epsin, out_fx,
                                         d0_w, d0_b, d0_g, d0_be, d0_m, d0_v, cluster,
                                         out_z, out_mu, out_lv, out_q, out_gz, dbuf);
    dim3 dec_grid((DQ + 63) / 64, NN / 64);
    k_dec_out<<<dec_grid, 256, 0, stream>>>(dbuf, out_w, out_b, out_de);
}